// Round 3
// baseline (197.806 us; speedup 1.0000x reference)
//
#include <hip/hip_runtime.h>

// mp: [1, 21, 16, 256, 256] fp32
#define CC   21
#define DD   16
#define HH   256
#define WW   256
#define HWP  (HH * WW)      // 65536
#define DHW  (DD * HWP)     // 1048576

typedef float f4a __attribute__((ext_vector_type(4), aligned(16)));
typedef float f2a __attribute__((ext_vector_type(2), aligned(8)));
__device__ __forceinline__ f4a f4add(f4a a, f4a b) { return a + b; }

// Non-draining barrier: LDS visibility only (lgkmcnt), vmcnt stays counted ->
// register prefetch loads survive the barrier (plain __syncthreads would emit
// s_waitcnt vmcnt(0) and drain the pipeline every tile).
#define BAR()                                                \
    do {                                                     \
        asm volatile("s_waitcnt lgkmcnt(0)" ::: "memory");   \
        __builtin_amdgcn_s_barrier();                        \
        asm volatile("" ::: "memory");                       \
    } while (0)

// ---------------------------------------------------------------------------
// K1: D-blur (registers) + H-blur (LDS), persistent blocks, software-pipelined:
// tile t+1's 12 global loads are issued right after tile t's stage-compute and
// stay in flight across both (non-draining) barriers and the whole H-pass.
// Per-tile arithmetic identical to the verified round-1/2 kernel.
// ---------------------------------------------------------------------------
#define AROW 36
#define PYN  12
#define A_SZ (DD * PYN * AROW)   // 27648 B -> 5 blocks/CU

#define NT1  (8 * 32 * CC)       // 5376 tiles
#define G1   1280                // 5 blocks/CU x 256 CU

__device__ __forceinline__ void issue_tile_loads(const float* __restrict__ mp,
                                                 int t, int s, int py, int x4,
                                                 f4a (&L)[12]) {
    const int xb = t & 7;
    const int yb = (t >> 3) & 31;
    const int ch = t >> 8;
    const int h  = min(HH - 1, max(0, yb * 8 + py - 2));
    const float* colp = mp + (size_t)ch * DHW + (size_t)h * WW + xb * 32 + x4 * 4;
#pragma unroll
    for (int m = 0; m < 12; ++m) {
        const int dz = s * 8 + m;                     // staged plane 0..19
        const int d  = min(DD - 1, max(0, dz - 2));   // replicate clamp in D
        L[m] = *(const f4a*)(colp + (size_t)d * HWP);
    }
}

__global__ __launch_bounds__(256, 5) void dh_blur_kernel(const float* __restrict__ mp,
                                                         float* __restrict__ out) {
    __shared__ float A[A_SZ];
    const int tid = threadIdx.x;
    const int s   = (tid >= 96) ? 1 : 0;
    const int col = (tid < 192) ? (tid - s * 96) : 0;
    const int py  = col >> 3;              // 0..11
    const int x4  = col & 7;               // quad 0..7
    const bool ldr = (tid < 192);

    f4a L[12];
    if (ldr) issue_tile_loads(mp, blockIdx.x, s, py, x4, L);   // prologue

    for (int t = blockIdx.x; t < NT1; t += G1) {
        const int xb = t & 7;
        const int yb = (t >> 3) & 31;
        const int ch = t >> 8;
        const int w0 = xb * 32;
        const int h0 = yb * 8;

        // stage-compute: consume L (auto vmcnt waits), sliding 5-tap D-sum
        if (ldr) {
            f4a sum = f4add(f4add(f4add(L[0], L[1]), f4add(L[2], L[3])), L[4]);
#pragma unroll
            for (int i = 0; i < 8; ++i) {
                *(f4a*)(&A[((s * 8 + i) * PYN + py) * AROW + x4 * 4]) = sum;
                if (i < 7) sum = sum - L[i] + L[i + 5];
            }
        }

        // prefetch next tile's loads; they stay in flight across BAR + H-pass
        const int tn = t + G1;
        if (tn < NT1 && ldr) issue_tile_loads(mp, tn, s, py, x4, L);

        BAR();   // A ready (LDS visibility only; vmcnt untouched)

        // H pass: tt = dout*64 + y*8 + x4
#pragma unroll
        for (int it = 0; it < 4; ++it) {
            const int tt   = tid + it * 256;
            const int xx4  = tt & 7;
            const int y    = (tt >> 3) & 7;
            const int dout = tt >> 6;

            const float* b = &A[(dout * PYN + y) * AROW + xx4 * 4];
            f4a a = *(const f4a*)b;
#pragma unroll
            for (int k = 1; k < 5; ++k) a = f4add(a, *(const f4a*)(b + k * AROW));

            *(f4a*)(out + (size_t)ch * DHW + (size_t)dout * HWP
                    + (h0 + y) * WW + w0 + xx4 * 4) = a;
        }

        BAR();   // A consumed; safe to overwrite next iteration
    }
}

// ---------------------------------------------------------------------------
// K2: W-blur + weighted-median, no LDS, no barriers. One thread = one aligned
// quad of 4 pixels; one WAVE = exactly one (d,h) row (64 quads), so in-place
// is race-free: all of a row's loads precede its stores within the same wave.
// W window w-2..w+5 = float2 + float4 + float2, all aligned, clamped in-row.
// Reads are LLC-warm (K1 just wrote the 88 MB intermediate; LLC = 256 MB).
// Arithmetic: identical associativity to the verified kernels.
// ---------------------------------------------------------------------------
__global__ __launch_bounds__(256, 4) void wmedian_kernel(float* __restrict__ y4) {
    const int g = blockIdx.x * 256 + threadIdx.x;   // spatial quad id
    const int q = g & 63;                           // quad within row
    const size_t base = (size_t)g * 4;

    float v[CC][4];
    float tot[4] = {0.f, 0.f, 0.f, 0.f};
#pragma unroll
    for (int c = 0; c < CC; ++c) {
        const float* p = y4 + (size_t)c * DHW + base;
        const f4a M = *(const f4a*)(p);
        f2a l2 = *(const f2a*)(p + ((q == 0) ? 0 : -2));
        f2a r2 = *(const f2a*)(p + ((q == 63) ? 0 : 4));
        if (q == 0)  { l2.x = M.x; l2.y = M.x; }     // replicate w=0
        if (q == 63) { r2.x = M.w; r2.y = M.w; }     // replicate w=255
        const float e0 = l2.x, e1 = l2.y, e2 = M.x, e3 = M.y;
        const float e4 = M.z,  e5 = M.w,  e6 = r2.x, e7 = r2.y;
        v[c][0] = ((((e0 + e1) + e2) + e3) + e4);    // same W order as verified
        v[c][1] = ((((e1 + e2) + e3) + e4) + e5);
        v[c][2] = ((((e2 + e3) + e4) + e5) + e6);
        v[c][3] = ((((e3 + e4) + e5) + e6) + e7);
#pragma unroll
        for (int pp = 0; pp < 4; ++pp) tot[pp] += v[c][pp];
    }

    float inv[4];
#pragma unroll
    for (int pp = 0; pp < 4; ++pp) inv[pp] = 1.0f / tot[pp];

    float sacc[4] = {0.f, 0.f, 0.f, 0.f};
    float v0[4], v1[4];
    int m0[4] = {0, 0, 0, 0}, m1[4] = {0, 0, 0, 0};
#pragma unroll
    for (int c = 0; c < CC; ++c) {
#pragma unroll
        for (int pp = 0; pp < 4; ++pp) {
            const float yn = v[c][pp] * inv[pp];
            const float sn = sacc[pp] + yn;
            if (c == 0) { v0[pp] = yn; v1[pp] = yn; }                              // defaults
            if (v[c][pp] > 0.f && sn < 0.5f) { m0[pp] = c; v0[pp] = yn; }          // last qualifying
            if (m1[pp] == 0 && c > 0 && sn > 0.5f) { m1[pp] = c; v1[pp] = yn; }    // first qualifying
            sacc[pp] = sn;
        }
    }

#pragma unroll
    for (int c = 0; c < CC; ++c) {
        f4a o;
        o.x = (c == m0[0]) ? v0[0] : ((c == m1[0]) ? v1[0] : 0.f);
        o.y = (c == m0[1]) ? v0[1] : ((c == m1[1]) ? v1[1] : 0.f);
        o.z = (c == m0[2]) ? v0[2] : ((c == m1[2]) ? v1[2] : 0.f);
        o.w = (c == m0[3]) ? v0[3] : ((c == m1[3]) ? v1[3] : 0.f);
        *(f4a*)(y4 + (size_t)c * DHW + base) = o;
    }
}

extern "C" void kernel_launch(void* const* d_in, const int* in_sizes, int n_in,
                              void* d_out, int out_size, void* d_ws, size_t ws_size,
                              hipStream_t stream) {
    const float* mp = (const float*)d_in[0];
    float* out = (float*)d_out;

    dh_blur_kernel<<<G1, 256, 0, stream>>>(mp, out);          // 1280 persistent blocks
    wmedian_kernel<<<(DHW / 4) / 256, 256, 0, stream>>>(out); // 1024 blocks
}